// Round 1
// baseline (533.562 us; speedup 1.0000x reference)
//
#include <hip/hip_runtime.h>
#include <hip/hip_fp16.h>

// AttentionQV0: LN -> QKV -> QK^T -> dw-convs -> 1x1 conv -> BN+SiLU -> softmax -> PV -> out proj
// B=2,P=2,N=1024,DIM=256,HEADS=8,DH=64,HW=32,C=1024. 32 "images" of 1024x1024 scores.
// Workspace requirement: 149 MB (region0 64MB D->S, region1 64MB Aconv->P, statics ~21MB).

#define DEV __device__ __forceinline__

typedef __attribute__((ext_vector_type(8))) _Float16 f16x8;
typedef __attribute__((ext_vector_type(4))) float f32x4;

DEV float h2f_bits(unsigned short u) { __half h; *reinterpret_cast<unsigned short*>(&h) = u; return __half2float(h); }
DEV unsigned short f2h_bits(float f) { __half h = __float2half(f); return *reinterpret_cast<unsigned short*>(&h); }

// ---------------- prep: cast/transpose weights to f16 ----------------
__global__ __launch_bounds__(256) void prep_kernel(
    const float* __restrict__ wqkv, const float* __restrict__ w1x1,
    const float* __restrict__ wout,
    __half* __restrict__ WQKVT, __half* __restrict__ W1X1H, __half* __restrict__ WOTT) {
  int i0 = blockIdx.x * 256 + threadIdx.x;
  int stride = gridDim.x * 256;
  for (int i = i0; i < 1536 * 256; i += stride) {          // WQKVT[j][k] = wqkv[k][j]
    int j = i >> 8, k = i & 255;
    WQKVT[i] = __float2half(wqkv[k * 1536 + j]);
  }
  for (int i = i0; i < 1024 * 1024; i += stride)           // straight cast (row o, col c)
    W1X1H[i] = __float2half(w1x1[i]);
  for (int i = i0; i < 256 * 512; i += stride) {           // WOTT[j][k] = wout[k][j]
    int j = i >> 9, k = i & 511;
    WOTT[i] = __float2half(wout[k * 256 + j]);
  }
}

// ---------------- LayerNorm (row = token, 256 threads) ----------------
__global__ __launch_bounds__(256) void ln_kernel(const float* __restrict__ x,
    const float* __restrict__ g, const float* __restrict__ b, __half* __restrict__ XN) {
  int row = blockIdx.x;
  int tid = threadIdx.x, lane = tid & 63, wid = tid >> 6;
  float xv = x[(size_t)row * 256 + tid];
  float s = xv, q = xv * xv;
#pragma unroll
  for (int off = 32; off; off >>= 1) { s += __shfl_xor(s, off); q += __shfl_xor(q, off); }
  __shared__ float rs[4], rq[4];
  if (lane == 0) { rs[wid] = s; rq[wid] = q; }
  __syncthreads();
  s = rs[0] + rs[1] + rs[2] + rs[3];
  q = rq[0] + rq[1] + rq[2] + rq[3];
  float mu = s * (1.f / 256.f);
  float var = q * (1.f / 256.f) - mu * mu;
  float r = rsqrtf(var + 1e-5f);
  XN[(size_t)row * 256 + tid] = __float2half((xv - mu) * r * g[tid] + b[tid]);
}

// ---------------- generic BT GEMM: C[i][j] = sum_k A[i][k]*B[j][k] ----------------
// 128-wide tiles, BK=32, 256 threads (4 waves), mfma_f32_16x16x32_f16, global_load_lds(16B).
template <int BM, int BN, int BK, int WGN, int FM, int FN, class Epi>
__global__ __launch_bounds__(256) void gemm_bt(
    const __half* __restrict__ A, long long aStride,
    const __half* __restrict__ B, long long bStride,
    int K, Epi epi) {
  constexpr int CPR = BK / 8;                 // 16B chunks per row
  constexpr int NCA = (BM * BK) / (8 * 256);
  constexpr int NCB = (BN * BK) / (8 * 256);
  __shared__ __align__(16) __half smA[BM * BK];
  __shared__ __align__(16) __half smB[BN * BK];
  const int tid = threadIdx.x;
  const int lane = tid & 63, wid = tid >> 6;
  const int wr = wid / WGN, wc = wid % WGN;
  const int img = blockIdx.z;
  const int row0 = blockIdx.x * BM;
  const int col0 = blockIdx.y * BN;
  const __half* Ab = A + (size_t)((long long)img * aStride);
  const __half* Bb = B + (size_t)((long long)img * bStride);
  f32x4 acc[FM][FN] = {};
  const int lr = lane & 15;
  const int kr = (lane >> 4) * 8;
  for (int kt = 0; kt < K; kt += BK) {
#pragma unroll
    for (int it = 0; it < NCA; ++it) {
      int e = it * 256 + tid;
      int r = e / CPR, c = e % CPR;
      __builtin_amdgcn_global_load_lds(
          (const __attribute__((address_space(1))) unsigned int*)(Ab + (size_t)(row0 + r) * K + kt + c * 8),
          (__attribute__((address_space(3))) unsigned int*)(smA + r * BK + c * 8),
          16, 0, 0);
    }
#pragma unroll
    for (int it = 0; it < NCB; ++it) {
      int e = it * 256 + tid;
      int r = e / CPR, c = e % CPR;
      __builtin_amdgcn_global_load_lds(
          (const __attribute__((address_space(1))) unsigned int*)(Bb + (size_t)(col0 + r) * K + kt + c * 8),
          (__attribute__((address_space(3))) unsigned int*)(smB + r * BK + c * 8),
          16, 0, 0);
    }
    __syncthreads();
    f16x8 av[FM], bv[FN];
#pragma unroll
    for (int i = 0; i < FM; ++i)
      av[i] = *reinterpret_cast<const f16x8*>(&smA[(wr * FM * 16 + i * 16 + lr) * BK + kr]);
#pragma unroll
    for (int j = 0; j < FN; ++j)
      bv[j] = *reinterpret_cast<const f16x8*>(&smB[(wc * FN * 16 + j * 16 + lr) * BK + kr]);
#pragma unroll
    for (int i = 0; i < FM; ++i)
#pragma unroll
      for (int j = 0; j < FN; ++j)
        acc[i][j] = __builtin_amdgcn_mfma_f32_16x16x32_f16(av[i], bv[j], acc[i][j], 0, 0, 0);
    __syncthreads();
  }
  const int orow = row0 + wr * FM * 16 + (lane >> 4) * 4;
  const int ocol = col0 + wc * FN * 16 + lr;
#pragma unroll
  for (int i = 0; i < FM; ++i)
#pragma unroll
    for (int j = 0; j < FN; ++j)
#pragma unroll
      for (int q = 0; q < 4; ++q)
        epi.store(img, orow + i * 16 + q, ocol + j * 16, acc[i][j][q]);
}

// ---------------- epilogues ----------------
struct EpiQKV {  // rows t in [0,4096), cols j in [0,1536)
  __half *Q, *K, *V;
  DEV void store(int, int t, int j, float v) const {
    int part = j >> 9, inner = j & 511;
    int h = inner >> 6, d = inner & 63;
    int bp = t >> 10, n = t & 1023;
    size_t img = (size_t)(bp * 8 + h);
    if (part == 0)       Q[(img * 1024 + n) * 64 + d] = __float2half(v * 0.125f); // fold DH^-0.5
    else if (part == 1)  K[(img * 1024 + n) * 64 + d] = __float2half(v);
    else                 V[(img * 64 + d) * 1024 + n] = __float2half(v);          // V transposed
  }
};
struct EpiQK {   // D[img][n][m], natural layout
  __half* D;
  DEV void store(int img, int n, int m, float v) const {
    D[((size_t)img << 20) + n * 1024 + m] = __float2half(v);
  }
};
struct Epi1x1 {  // rows o (out channel), cols s (spatial). BN+SiLU then permute to S[n][m].
  __half* S;
  const float *g, *b, *m, *vv;
  DEV void store(int img, int o, int s, float acc) const {
    float inv = rsqrtf(vv[o] + 1e-5f);
    float t = (acc - m[o]) * (inv * g[o]) + b[o];
    float val = t / (1.f + __expf(-t));
    int n  = (o >> 5) * 32 + (s >> 5);   // h1'*32 + w1
    int mm = (o & 31) * 32 + (s & 31);   // h2'*32 + w2
    S[((size_t)img << 20) + n * 1024 + mm] = __float2half(val);
  }
};
struct EpiPV {   // rows n, cols d -> O[(bp*1024+n)][h*64+d]
  __half* O;
  DEV void store(int img, int n, int d, float v) const {
    int bp = img >> 3, h = img & 7;
    O[((size_t)(bp * 1024 + n)) * 512 + h * 64 + d] = __float2half(v);
  }
};
struct EpiOut {  // rows t, cols j -> out f32 + bias
  float* out; const float* bias;
  DEV void store(int, int t, int j, float v) const {
    out[(size_t)t * 256 + j] = v + bias[j];
  }
};

// ---------------- fused depthwise convs: D[n][m] -> Aconv^T[s][c] ----------------
__global__ __launch_bounds__(256) void conv_kernel(const __half* __restrict__ D,
    const float* __restrict__ wc1, const float* __restrict__ wc2, __half* __restrict__ AC) {
  int idx0 = blockIdx.x * 256 + threadIdx.x;
  int stride = gridDim.x * 256;
  for (int idx = idx0; idx < (1 << 25); idx += stride) {
    int c = idx & 1023;
    int s = (idx >> 10) & 1023;
    int img = idx >> 20;
    int h1 = c >> 5, h2 = c & 31, w1 = s >> 5, w2 = s & 31;
    int n0 = h1 * 32 + w1;
    int n1 = h1 * 32 + (w1 < 31 ? w1 + 1 : 30);   // reflect: row 31's neighbor is 30
    int m0 = h2 * 32 + w2;
    int m1 = h2 * 32 + (w2 < 31 ? w2 + 1 : 30);
    const __half* Di = D + ((size_t)img << 20);
    float a00 = __half2float(Di[n0 * 1024 + m0]);
    float a01 = __half2float(Di[n0 * 1024 + m1]);
    float a10 = __half2float(Di[n1 * 1024 + m0]);
    float a11 = __half2float(Di[n1 * 1024 + m1]);
    float u0 = wc1[2 * c], u1 = wc1[2 * c + 1];   // conv along w2 first
    float v0 = wc2[2 * c], v1 = wc2[2 * c + 1];   // then along w1
    AC[idx] = __float2half(v0 * (u0 * a00 + u1 * a01) + v1 * (u0 * a10 + u1 * a11));
  }
}

// ---------------- row softmax: S[row][0..1024) f16 -> P f16 ----------------
__global__ __launch_bounds__(256) void softmax_kernel(const __half* __restrict__ S,
                                                      __half* __restrict__ P) {
  int row = blockIdx.x;
  int tid = threadIdx.x, lane = tid & 63, wid = tid >> 6;
  const __half* Sr = S + ((size_t)row << 10);
  ushort4 raw = reinterpret_cast<const ushort4*>(Sr)[tid];
  float v0 = h2f_bits(raw.x), v1 = h2f_bits(raw.y), v2 = h2f_bits(raw.z), v3 = h2f_bits(raw.w);
  float mx = fmaxf(fmaxf(v0, v1), fmaxf(v2, v3));
#pragma unroll
  for (int off = 32; off; off >>= 1) mx = fmaxf(mx, __shfl_xor(mx, off));
  __shared__ float rm[4], rsum[4];
  if (lane == 0) rm[wid] = mx;
  __syncthreads();
  mx = fmaxf(fmaxf(rm[0], rm[1]), fmaxf(rm[2], rm[3]));
  float e0 = __expf(v0 - mx), e1 = __expf(v1 - mx), e2 = __expf(v2 - mx), e3 = __expf(v3 - mx);
  float sm = e0 + e1 + e2 + e3;
#pragma unroll
  for (int off = 32; off; off >>= 1) sm += __shfl_xor(sm, off);
  if (lane == 0) rsum[wid] = sm;
  __syncthreads();
  sm = rsum[0] + rsum[1] + rsum[2] + rsum[3];
  float inv = 1.f / sm;
  ushort4 o4;
  o4.x = f2h_bits(e0 * inv); o4.y = f2h_bits(e1 * inv);
  o4.z = f2h_bits(e2 * inv); o4.w = f2h_bits(e3 * inv);
  reinterpret_cast<ushort4*>(P + ((size_t)row << 10))[tid] = o4;
}

extern "C" void kernel_launch(void* const* d_in, const int* in_sizes, int n_in,
                              void* d_out, int out_size, void* d_ws, size_t ws_size,
                              hipStream_t stream) {
  const float* x     = (const float*)d_in[0];
  const float* ln_g  = (const float*)d_in[1];
  const float* ln_b  = (const float*)d_in[2];
  const float* w_qkv = (const float*)d_in[3];
  const float* wc1   = (const float*)d_in[4];
  const float* wc2   = (const float*)d_in[5];
  const float* w1x1  = (const float*)d_in[6];
  const float* bn_g  = (const float*)d_in[7];
  const float* bn_b  = (const float*)d_in[8];
  const float* bn_m  = (const float*)d_in[9];
  const float* bn_v  = (const float*)d_in[10];
  const float* w_out = (const float*)d_in[11];
  const float* b_out = (const float*)d_in[12];
  float* out = (float*)d_out;

  const size_t MB = 1024 * 1024;
  char* ws = (char*)d_ws;
  // region0 (64MB): D (QK output), later overwritten by S (1x1 output)
  __half* Db = (__half*)ws;
  __half* Sh = (__half*)ws;
  // region1 (64MB): Aconv^T, later overwritten by P (softmax output)
  __half* ACb = (__half*)(ws + 64 * MB);
  __half* Pb  = ACb;
  // statics
  char* p = ws + 128 * MB;
  __half* XN    = (__half*)p; p += 2 * MB;            // 4096x256
  __half* WQKVT = (__half*)p; p += 1536 * 256 * 2;    // 1536x256
  __half* W1X1H = (__half*)p; p += 2 * MB;            // 1024x1024
  __half* WOTT  = (__half*)p; p += 256 * 512 * 2;     // 256x512
  __half* Qb    = (__half*)p; p += 4 * MB;            // 32x1024x64 (scaled)
  __half* Kb    = (__half*)p; p += 4 * MB;            // 32x1024x64
  __half* Vtb   = (__half*)p; p += 4 * MB;            // 32x64x1024
  __half* Ob    = (__half*)p; p += 4 * MB;            // 4096x512

  prep_kernel<<<2048, 256, 0, stream>>>(w_qkv, w1x1, w_out, WQKVT, W1X1H, WOTT);
  ln_kernel<<<4096, 256, 0, stream>>>(x, ln_g, ln_b, XN);

  { EpiQKV e{Qb, Kb, Vtb};
    gemm_bt<128, 128, 32, 2, 4, 4, EpiQKV><<<dim3(32, 12, 1), 256, 0, stream>>>(
        XN, 0, WQKVT, 0, 256, e); }

  { EpiQK e{Db};
    gemm_bt<128, 128, 32, 2, 4, 4, EpiQK><<<dim3(8, 8, 32), 256, 0, stream>>>(
        Qb, 65536, Kb, 65536, 64, e); }

  conv_kernel<<<8192, 256, 0, stream>>>(Db, wc1, wc2, ACb);

  { Epi1x1 e{Sh, bn_g, bn_b, bn_m, bn_v};
    gemm_bt<128, 128, 32, 2, 4, 4, Epi1x1><<<dim3(8, 8, 32), 256, 0, stream>>>(
        W1X1H, 0, ACb, 1 << 20, 1024, e); }

  softmax_kernel<<<32768, 256, 0, stream>>>(Sh, Pb);

  { EpiPV e{Ob};
    gemm_bt<128, 64, 32, 2, 4, 2, EpiPV><<<dim3(8, 1, 32), 256, 0, stream>>>(
        Pb, 1 << 20, Vtb, 65536, 1024, e); }

  { EpiOut e{out, b_out};
    gemm_bt<128, 128, 32, 2, 4, 4, EpiOut><<<dim3(32, 2, 1), 256, 0, stream>>>(
        Ob, 0, WOTT, 0, 512, e); }
}

// Round 2
// 286.356 us; speedup vs baseline: 1.8633x; 1.8633x over previous
//
#include <hip/hip_runtime.h>
#include <hip/hip_fp16.h>

// AttentionQV0: LN -> QKV -> QK^T -> dw-convs -> 1x1 conv -> BN+SiLU -> softmax -> PV -> out proj
// B=2,P=2,N=1024,DIM=256,HEADS=8,DH=64,HW=32,C=1024. 32 "images" of 1024x1024 scores.
// Workspace requirement: 149 MB (region0 64MB D->S, region1 64MB Aconv->P, statics ~21MB).

#define DEV __device__ __forceinline__

typedef __attribute__((ext_vector_type(8))) _Float16 f16x8;
typedef __attribute__((ext_vector_type(4))) float f32x4;

DEV float h2f_bits(unsigned short u) { __half h; *reinterpret_cast<unsigned short*>(&h) = u; return __half2float(h); }
DEV unsigned short f2h_bits(float f) { __half h = __float2half(f); return *reinterpret_cast<unsigned short*>(&h); }

// ---------------- prep: cast/transpose weights to f16 ----------------
__global__ __launch_bounds__(256) void prep_kernel(
    const float* __restrict__ wqkv, const float* __restrict__ w1x1,
    const float* __restrict__ wout,
    __half* __restrict__ WQKVT, __half* __restrict__ W1X1H, __half* __restrict__ WOTT) {
  int i0 = blockIdx.x * 256 + threadIdx.x;
  int stride = gridDim.x * 256;
  for (int i = i0; i < 1536 * 256; i += stride) {          // WQKVT[j][k] = wqkv[k][j]
    int j = i >> 8, k = i & 255;
    WQKVT[i] = __float2half(wqkv[k * 1536 + j]);
  }
  for (int i = i0; i < 1024 * 1024; i += stride)           // straight cast (row o, col c)
    W1X1H[i] = __float2half(w1x1[i]);
  for (int i = i0; i < 256 * 512; i += stride) {           // WOTT[j][k] = wout[k][j]
    int j = i >> 9, k = i & 511;
    WOTT[i] = __float2half(wout[k * 256 + j]);
  }
}

// ---------------- LayerNorm (row = token, 256 threads) ----------------
__global__ __launch_bounds__(256) void ln_kernel(const float* __restrict__ x,
    const float* __restrict__ g, const float* __restrict__ b, __half* __restrict__ XN) {
  int row = blockIdx.x;
  int tid = threadIdx.x, lane = tid & 63, wid = tid >> 6;
  float xv = x[(size_t)row * 256 + tid];
  float s = xv, q = xv * xv;
#pragma unroll
  for (int off = 32; off; off >>= 1) { s += __shfl_xor(s, off); q += __shfl_xor(q, off); }
  __shared__ float rs[4], rq[4];
  if (lane == 0) { rs[wid] = s; rq[wid] = q; }
  __syncthreads();
  s = rs[0] + rs[1] + rs[2] + rs[3];
  q = rq[0] + rq[1] + rq[2] + rq[3];
  float mu = s * (1.f / 256.f);
  float var = q * (1.f / 256.f) - mu * mu;
  float r = rsqrtf(var + 1e-5f);
  XN[(size_t)row * 256 + tid] = __float2half((xv - mu) * r * g[tid] + b[tid]);
}

// ---------------- generic BT GEMM: C[i][j] = sum_k A[i][k]*B[j][k] ----------------
// 128-wide tiles, BK=32, 256 threads (4 waves), mfma_f32_16x16x32_f16, global_load_lds(16B).
template <int BM, int BN, int BK, int WGN, int FM, int FN, class Epi>
__global__ __launch_bounds__(256) void gemm_bt(
    const __half* __restrict__ A, long long aStride,
    const __half* __restrict__ B, long long bStride,
    int K, Epi epi) {
  constexpr int CPR = BK / 8;                 // 16B chunks per row
  constexpr int NCA = (BM * BK) / (8 * 256);
  constexpr int NCB = (BN * BK) / (8 * 256);
  __shared__ __align__(16) __half smA[BM * BK];
  __shared__ __align__(16) __half smB[BN * BK];
  const int tid = threadIdx.x;
  const int lane = tid & 63, wid = tid >> 6;
  const int wr = wid / WGN, wc = wid % WGN;
  const int img = blockIdx.z;
  const int row0 = blockIdx.x * BM;
  const int col0 = blockIdx.y * BN;
  const __half* Ab = A + (size_t)((long long)img * aStride);
  const __half* Bb = B + (size_t)((long long)img * bStride);
  f32x4 acc[FM][FN] = {};
  const int lr = lane & 15;
  const int kr = (lane >> 4) * 8;
  for (int kt = 0; kt < K; kt += BK) {
#pragma unroll
    for (int it = 0; it < NCA; ++it) {
      int e = it * 256 + tid;
      int r = e / CPR, c = e % CPR;
      __builtin_amdgcn_global_load_lds(
          (const __attribute__((address_space(1))) unsigned int*)(Ab + (size_t)(row0 + r) * K + kt + c * 8),
          (__attribute__((address_space(3))) unsigned int*)(smA + r * BK + c * 8),
          16, 0, 0);
    }
#pragma unroll
    for (int it = 0; it < NCB; ++it) {
      int e = it * 256 + tid;
      int r = e / CPR, c = e % CPR;
      __builtin_amdgcn_global_load_lds(
          (const __attribute__((address_space(1))) unsigned int*)(Bb + (size_t)(col0 + r) * K + kt + c * 8),
          (__attribute__((address_space(3))) unsigned int*)(smB + r * BK + c * 8),
          16, 0, 0);
    }
    __syncthreads();
    f16x8 av[FM], bv[FN];
#pragma unroll
    for (int i = 0; i < FM; ++i)
      av[i] = *reinterpret_cast<const f16x8*>(&smA[(wr * FM * 16 + i * 16 + lr) * BK + kr]);
#pragma unroll
    for (int j = 0; j < FN; ++j)
      bv[j] = *reinterpret_cast<const f16x8*>(&smB[(wc * FN * 16 + j * 16 + lr) * BK + kr]);
#pragma unroll
    for (int i = 0; i < FM; ++i)
#pragma unroll
      for (int j = 0; j < FN; ++j)
        acc[i][j] = __builtin_amdgcn_mfma_f32_16x16x32_f16(av[i], bv[j], acc[i][j], 0, 0, 0);
    __syncthreads();
  }
  const int orow = row0 + wr * FM * 16 + (lane >> 4) * 4;
  const int ocol = col0 + wc * FN * 16 + lr;
#pragma unroll
  for (int i = 0; i < FM; ++i)
#pragma unroll
    for (int j = 0; j < FN; ++j)
#pragma unroll
      for (int q = 0; q < 4; ++q)
        epi.store(img, orow + i * 16 + q, ocol + j * 16, acc[i][j][q]);
}

// ---------------- epilogues ----------------
struct EpiQKV {  // rows t in [0,4096), cols j in [0,1536)
  __half *Q, *K, *V;
  DEV void store(int, int t, int j, float v) const {
    int part = j >> 9, inner = j & 511;
    int h = inner >> 6, d = inner & 63;
    int bp = t >> 10, n = t & 1023;
    size_t img = (size_t)(bp * 8 + h);
    if (part == 0)       Q[(img * 1024 + n) * 64 + d] = __float2half(v * 0.125f); // fold DH^-0.5
    else if (part == 1)  K[(img * 1024 + n) * 64 + d] = __float2half(v);
    else                 V[(img * 64 + d) * 1024 + n] = __float2half(v);          // V transposed
  }
};
struct EpiQK {   // D[img][n][m], natural layout
  __half* D;
  DEV void store(int img, int n, int m, float v) const {
    D[((size_t)img << 20) + n * 1024 + m] = __float2half(v);
  }
};
struct Epi1x1 {  // rows o (out channel), cols s (spatial). BN+SiLU then permute to S[n][m].
  __half* S;
  const float *g, *b, *m, *vv;
  DEV void store(int img, int o, int s, float acc) const {
    float inv = rsqrtf(vv[o] + 1e-5f);
    float t = (acc - m[o]) * (inv * g[o]) + b[o];
    float val = t / (1.f + __expf(-t));
    int n  = (o >> 5) * 32 + (s >> 5);   // h1'*32 + w1
    int mm = (o & 31) * 32 + (s & 31);   // h2'*32 + w2
    S[((size_t)img << 20) + n * 1024 + mm] = __float2half(val);
  }
};
struct EpiPV {   // rows n, cols d -> O[(bp*1024+n)][h*64+d]
  __half* O;
  DEV void store(int img, int n, int d, float v) const {
    int bp = img >> 3, h = img & 7;
    O[((size_t)(bp * 1024 + n)) * 512 + h * 64 + d] = __float2half(v);
  }
};
struct EpiOut {  // rows t, cols j -> out f32 + bias
  float* out; const float* bias;
  DEV void store(int, int t, int j, float v) const {
    out[(size_t)t * 256 + j] = v + bias[j];
  }
};

// ---------------- fused depthwise convs as LDS-tiled transpose ----------------
// block = (img, h1). For each w1: read D rows n0=h1*32+w1, n1 (contiguous, coalesced),
// 4-tap conv in registers (per-thread channel weights), transpose (h2,w2)->(w2,h2)
// through padded LDS, write AC[s=w1*32+w2][c=h1*32+h2] coalesced.
__global__ __launch_bounds__(256) void conv_t_kernel(const __half* __restrict__ D,
    const float* __restrict__ wc1, const float* __restrict__ wc2,
    __half* __restrict__ AC) {
  const int img = blockIdx.x >> 5, h1 = blockIdx.x & 31;
  const __half* Di = D + ((size_t)img << 20) + (size_t)h1 * 32768;  // rows n = h1*32 + w1
  __half* ACi = AC + ((size_t)img << 20) + h1 * 32;
  const int tid = threadIdx.x;
  const int h2 = tid >> 3;          // channel-in-block (fixed per thread)
  const int w2 = (tid & 7) * 4;     // first w2 of this thread's 4 elems
  const int m = tid * 4;            // = h2*32 + w2
  const int c = h1 * 32 + h2;
  const float u0 = wc1[2 * c], u1 = wc1[2 * c + 1];   // conv along w2
  const float v0 = wc2[2 * c], v1 = wc2[2 * c + 1];   // conv along w1
  const int w2o = tid >> 3, h2o = (tid & 7) * 4;      // write-phase mapping
  __shared__ __half T[32][36];                        // [w2][h2], padded
  for (int w1 = 0; w1 < 32; ++w1) {
    const int w1n = (w1 < 31) ? w1 + 1 : 30;          // reflect bottom
    const __half* r0 = Di + w1 * 1024;
    const __half* r1 = Di + w1n * 1024;
    float a0[5], a1[5];
    ushort4 x0 = *reinterpret_cast<const ushort4*>(r0 + m);
    ushort4 x1 = *reinterpret_cast<const ushort4*>(r1 + m);
    a0[0] = h2f_bits(x0.x); a0[1] = h2f_bits(x0.y); a0[2] = h2f_bits(x0.z); a0[3] = h2f_bits(x0.w);
    a1[0] = h2f_bits(x1.x); a1[1] = h2f_bits(x1.y); a1[2] = h2f_bits(x1.z); a1[3] = h2f_bits(x1.w);
    if (w2 != 28) { a0[4] = __half2float(r0[m + 4]); a1[4] = __half2float(r1[m + 4]); }
    else          { a0[4] = 0.f;                      a1[4] = 0.f; }
#pragma unroll
    for (int j = 0; j < 4; ++j) {
      int jn = (w2 + j < 31) ? j + 1 : j - 1;         // reflect right (w2=31 -> 30)
      float val = v0 * (u0 * a0[j] + u1 * a0[jn]) + v1 * (u0 * a1[j] + u1 * a1[jn]);
      T[w2 + j][h2] = __float2half(val);
    }
    __syncthreads();
    ushort4 o = *reinterpret_cast<const ushort4*>(&T[w2o][h2o]);
    *reinterpret_cast<ushort4*>(ACi + (size_t)(w1 * 32 + w2o) * 1024 + h2o) = o;
    __syncthreads();
  }
}

// ---------------- row softmax: S[row][0..1024) f16 -> P f16 ----------------
__global__ __launch_bounds__(256) void softmax_kernel(const __half* __restrict__ S,
                                                      __half* __restrict__ P) {
  int row = blockIdx.x;
  int tid = threadIdx.x, lane = tid & 63, wid = tid >> 6;
  const __half* Sr = S + ((size_t)row << 10);
  ushort4 raw = reinterpret_cast<const ushort4*>(Sr)[tid];
  float v0 = h2f_bits(raw.x), v1 = h2f_bits(raw.y), v2 = h2f_bits(raw.z), v3 = h2f_bits(raw.w);
  float mx = fmaxf(fmaxf(v0, v1), fmaxf(v2, v3));
#pragma unroll
  for (int off = 32; off; off >>= 1) mx = fmaxf(mx, __shfl_xor(mx, off));
  __shared__ float rm[4], rsum[4];
  if (lane == 0) rm[wid] = mx;
  __syncthreads();
  mx = fmaxf(fmaxf(rm[0], rm[1]), fmaxf(rm[2], rm[3]));
  float e0 = __expf(v0 - mx), e1 = __expf(v1 - mx), e2 = __expf(v2 - mx), e3 = __expf(v3 - mx);
  float sm = e0 + e1 + e2 + e3;
#pragma unroll
  for (int off = 32; off; off >>= 1) sm += __shfl_xor(sm, off);
  if (lane == 0) rsum[wid] = sm;
  __syncthreads();
  sm = rsum[0] + rsum[1] + rsum[2] + rsum[3];
  float inv = 1.f / sm;
  ushort4 o4;
  o4.x = f2h_bits(e0 * inv); o4.y = f2h_bits(e1 * inv);
  o4.z = f2h_bits(e2 * inv); o4.w = f2h_bits(e3 * inv);
  reinterpret_cast<ushort4*>(P + ((size_t)row << 10))[tid] = o4;
}

extern "C" void kernel_launch(void* const* d_in, const int* in_sizes, int n_in,
                              void* d_out, int out_size, void* d_ws, size_t ws_size,
                              hipStream_t stream) {
  const float* x     = (const float*)d_in[0];
  const float* ln_g  = (const float*)d_in[1];
  const float* ln_b  = (const float*)d_in[2];
  const float* w_qkv = (const float*)d_in[3];
  const float* wc1   = (const float*)d_in[4];
  const float* wc2   = (const float*)d_in[5];
  const float* w1x1  = (const float*)d_in[6];
  const float* bn_g  = (const float*)d_in[7];
  const float* bn_b  = (const float*)d_in[8];
  const float* bn_m  = (const float*)d_in[9];
  const float* bn_v  = (const float*)d_in[10];
  const float* w_out = (const float*)d_in[11];
  const float* b_out = (const float*)d_in[12];
  float* out = (float*)d_out;

  const size_t MB = 1024 * 1024;
  char* ws = (char*)d_ws;
  // region0 (64MB): D (QK output), later overwritten by S (1x1 output)
  __half* Db = (__half*)ws;
  __half* Sh = (__half*)ws;
  // region1 (64MB): Aconv^T, later overwritten by P (softmax output)
  __half* ACb = (__half*)(ws + 64 * MB);
  __half* Pb  = ACb;
  // statics
  char* p = ws + 128 * MB;
  __half* XN    = (__half*)p; p += 2 * MB;            // 4096x256
  __half* WQKVT = (__half*)p; p += 1536 * 256 * 2;    // 1536x256
  __half* W1X1H = (__half*)p; p += 2 * MB;            // 1024x1024
  __half* WOTT  = (__half*)p; p += 256 * 512 * 2;     // 256x512
  __half* Qb    = (__half*)p; p += 4 * MB;            // 32x1024x64 (scaled)
  __half* Kb    = (__half*)p; p += 4 * MB;            // 32x1024x64
  __half* Vtb   = (__half*)p; p += 4 * MB;            // 32x64x1024
  __half* Ob    = (__half*)p; p += 4 * MB;            // 4096x512

  prep_kernel<<<2048, 256, 0, stream>>>(w_qkv, w1x1, w_out, WQKVT, W1X1H, WOTT);
  ln_kernel<<<4096, 256, 0, stream>>>(x, ln_g, ln_b, XN);

  { EpiQKV e{Qb, Kb, Vtb};
    gemm_bt<128, 128, 32, 2, 4, 4, EpiQKV><<<dim3(32, 12, 1), 256, 0, stream>>>(
        XN, 0, WQKVT, 0, 256, e); }

  { EpiQK e{Db};
    gemm_bt<128, 128, 32, 2, 4, 4, EpiQK><<<dim3(8, 8, 32), 256, 0, stream>>>(
        Qb, 65536, Kb, 65536, 64, e); }

  conv_t_kernel<<<1024, 256, 0, stream>>>(Db, wc1, wc2, ACb);

  { Epi1x1 e{Sh, bn_g, bn_b, bn_m, bn_v};
    gemm_bt<128, 128, 32, 2, 4, 4, Epi1x1><<<dim3(8, 8, 32), 256, 0, stream>>>(
        W1X1H, 0, ACb, 1 << 20, 1024, e); }

  softmax_kernel<<<32768, 256, 0, stream>>>(Sh, Pb);

  { EpiPV e{Ob};
    gemm_bt<128, 64, 32, 2, 4, 2, EpiPV><<<dim3(8, 1, 32), 256, 0, stream>>>(
        Pb, 1 << 20, Vtb, 65536, 1024, e); }

  { EpiOut e{out, b_out};
    gemm_bt<128, 128, 32, 2, 4, 4, EpiOut><<<dim3(32, 2, 1), 256, 0, stream>>>(
        Ob, 0, WOTT, 0, 512, e); }
}

// Round 3
// 278.644 us; speedup vs baseline: 1.9148x; 1.0277x over previous
//
#include <hip/hip_runtime.h>
#include <hip/hip_fp16.h>

// AttentionQV0: LN -> QKV -> QK^T -> dw-convs -> 1x1 conv -> BN+SiLU -> softmax -> PV -> out proj
// B=2,P=2,N=1024,DIM=256,HEADS=8,DH=64,HW=32,C=1024. 32 "images" of 1024x1024 scores.
// Workspace requirement: 149 MB (region0 64MB D->S, region1 64MB Aconv->P, statics ~21MB).

#define DEV __device__ __forceinline__

typedef __attribute__((ext_vector_type(8))) _Float16 f16x8;
typedef __attribute__((ext_vector_type(4))) float f32x4;

DEV float h2f_bits(unsigned short u) { __half h; *reinterpret_cast<unsigned short*>(&h) = u; return __half2float(h); }
DEV unsigned short f2h_bits(float f) { __half h = __float2half(f); return *reinterpret_cast<unsigned short*>(&h); }

// ---------------- prep: cast/transpose weights to f16 ----------------
__global__ __launch_bounds__(256) void prep_kernel(
    const float* __restrict__ wqkv, const float* __restrict__ w1x1,
    const float* __restrict__ wout,
    __half* __restrict__ WQKVT, __half* __restrict__ W1X1H, __half* __restrict__ WOTT) {
  int i0 = blockIdx.x * 256 + threadIdx.x;
  int stride = gridDim.x * 256;
  for (int i = i0; i < 1536 * 256; i += stride) {          // WQKVT[j][k] = wqkv[k][j]
    int j = i >> 8, k = i & 255;
    WQKVT[i] = __float2half(wqkv[k * 1536 + j]);
  }
  for (int i = i0; i < 1024 * 1024; i += stride)           // straight cast (row o, col c)
    W1X1H[i] = __float2half(w1x1[i]);
  for (int i = i0; i < 256 * 512; i += stride) {           // WOTT[j][k] = wout[k][j]
    int j = i >> 9, k = i & 511;
    WOTT[i] = __float2half(wout[k * 256 + j]);
  }
}

// ---------------- LayerNorm (row = token, 256 threads) ----------------
__global__ __launch_bounds__(256) void ln_kernel(const float* __restrict__ x,
    const float* __restrict__ g, const float* __restrict__ b, __half* __restrict__ XN) {
  int row = blockIdx.x;
  int tid = threadIdx.x, lane = tid & 63, wid = tid >> 6;
  float xv = x[(size_t)row * 256 + tid];
  float s = xv, q = xv * xv;
#pragma unroll
  for (int off = 32; off; off >>= 1) { s += __shfl_xor(s, off); q += __shfl_xor(q, off); }
  __shared__ float rs[4], rq[4];
  if (lane == 0) { rs[wid] = s; rq[wid] = q; }
  __syncthreads();
  s = rs[0] + rs[1] + rs[2] + rs[3];
  q = rq[0] + rq[1] + rq[2] + rq[3];
  float mu = s * (1.f / 256.f);
  float var = q * (1.f / 256.f) - mu * mu;
  float r = rsqrtf(var + 1e-5f);
  XN[(size_t)row * 256 + tid] = __float2half((xv - mu) * r * g[tid] + b[tid]);
}

// ---------------- generic BT GEMM: C[i][j] = sum_k A[i][k]*B[j][k] ----------------
// 128-wide tiles, BK=64, 256 threads (4 waves), mfma_f32_16x16x32_f16.
// Staging via global_load_lds(16B) with chunk swizzle c^(r&7) applied on the
// SOURCE address (LDS dest linear) and the same XOR on the ds_read -> LDS
// fragment reads are bank-conflict-free. XCD-aware block swizzle for L2 reuse.
template <int BM, int BN, int BK, int WGN, int FM, int FN, class Epi>
__global__ __launch_bounds__(256) void gemm_bt(
    const __half* __restrict__ A, long long aStride,
    const __half* __restrict__ B, long long bStride,
    int K, Epi epi) {
  constexpr int CPR = BK / 8;                 // 16B chunks per row
  constexpr int NCA = (BM * BK) / (8 * 256);
  constexpr int NCB = (BN * BK) / (8 * 256);
  constexpr int KSUB = BK / 32;               // mfma k-steps per tile
  __shared__ __align__(16) __half smA[BM * BK];
  __shared__ __align__(16) __half smB[BN * BK];
  const int tid = threadIdx.x;
  const int lane = tid & 63, wid = tid >> 6;
  const int wr = wid / WGN, wc = wid % WGN;
  // XCD-aware swizzle: consecutive logical blocks -> same XCD (grids are %8==0)
  const int gx = gridDim.x, gxy = gridDim.x * gridDim.y;
  const int nwg = gxy * gridDim.z;
  const int b_lin = blockIdx.x + blockIdx.y * gx + blockIdx.z * gxy;
  const int logical = (b_lin & 7) * (nwg >> 3) + (b_lin >> 3);
  const int bx = logical % gx, by = (logical / gx) % gridDim.y, bz = logical / gxy;
  const int img = bz;
  const int row0 = bx * BM;
  const int col0 = by * BN;
  const __half* Ab = A + (size_t)((long long)img * aStride);
  const __half* Bb = B + (size_t)((long long)img * bStride);
  f32x4 acc[FM][FN] = {};
  const int lr = lane & 15;
  const int kq = lane >> 4;                   // 0..3 (16B chunk within k-sub)
  for (int kt = 0; kt < K; kt += BK) {
#pragma unroll
    for (int it = 0; it < NCA; ++it) {
      int e = it * 256 + tid;
      int r = e / CPR, c = e % CPR;
      int sc = c ^ (r & 7);                   // inverse swizzle on SOURCE
      __builtin_amdgcn_global_load_lds(
          (const __attribute__((address_space(1))) unsigned int*)(Ab + (size_t)(row0 + r) * K + kt + sc * 8),
          (__attribute__((address_space(3))) unsigned int*)(smA + r * BK + c * 8),
          16, 0, 0);
    }
#pragma unroll
    for (int it = 0; it < NCB; ++it) {
      int e = it * 256 + tid;
      int r = e / CPR, c = e % CPR;
      int sc = c ^ (r & 7);
      __builtin_amdgcn_global_load_lds(
          (const __attribute__((address_space(1))) unsigned int*)(Bb + (size_t)(col0 + r) * K + kt + sc * 8),
          (__attribute__((address_space(3))) unsigned int*)(smB + r * BK + c * 8),
          16, 0, 0);
    }
    __syncthreads();
#pragma unroll
    for (int kk = 0; kk < KSUB; ++kk) {
      f16x8 av[FM], bv[FN];
#pragma unroll
      for (int i = 0; i < FM; ++i) {
        int row = wr * FM * 16 + i * 16 + lr;
        int ch = (kk * 4 + kq) ^ (lr & 7);    // swizzled read
        av[i] = *reinterpret_cast<const f16x8*>(&smA[row * BK + ch * 8]);
      }
#pragma unroll
      for (int j = 0; j < FN; ++j) {
        int row = wc * FN * 16 + j * 16 + lr;
        int ch = (kk * 4 + kq) ^ (lr & 7);
        bv[j] = *reinterpret_cast<const f16x8*>(&smB[row * BK + ch * 8]);
      }
#pragma unroll
      for (int i = 0; i < FM; ++i)
#pragma unroll
        for (int j = 0; j < FN; ++j)
          acc[i][j] = __builtin_amdgcn_mfma_f32_16x16x32_f16(av[i], bv[j], acc[i][j], 0, 0, 0);
    }
    __syncthreads();
  }
  const int orow = row0 + wr * FM * 16 + (lane >> 4) * 4;
  const int ocol = col0 + wc * FN * 16 + lr;
#pragma unroll
  for (int i = 0; i < FM; ++i)
#pragma unroll
    for (int j = 0; j < FN; ++j)
#pragma unroll
      for (int q = 0; q < 4; ++q)
        epi.store(img, orow + i * 16 + q, ocol + j * 16, acc[i][j][q]);
}

// ---------------- epilogues ----------------
struct EpiQKV {  // rows t in [0,4096), cols j in [0,1536)
  __half *Q, *K, *V;
  DEV void store(int, int t, int j, float v) const {
    int part = j >> 9, inner = j & 511;
    int h = inner >> 6, d = inner & 63;
    int bp = t >> 10, n = t & 1023;
    size_t img = (size_t)(bp * 8 + h);
    if (part == 0)       Q[(img * 1024 + n) * 64 + d] = __float2half(v * 0.125f); // fold DH^-0.5
    else if (part == 1)  K[(img * 1024 + n) * 64 + d] = __float2half(v);
    else                 V[(img * 64 + d) * 1024 + n] = __float2half(v);          // V transposed
  }
};
struct EpiQK {   // D[img][n][m], natural layout
  __half* D;
  DEV void store(int img, int n, int m, float v) const {
    D[((size_t)img << 20) + n * 1024 + m] = __float2half(v);
  }
};
struct Epi1x1 {  // rows o (out channel), cols s (spatial). BN+SiLU then permute to S[n][m].
  __half* S;
  const float *g, *b, *m, *vv;
  DEV void store(int img, int o, int s, float acc) const {
    float inv = rsqrtf(vv[o] + 1e-5f);
    float t = (acc - m[o]) * (inv * g[o]) + b[o];
    float val = t / (1.f + __expf(-t));
    int n  = (o >> 5) * 32 + (s >> 5);   // h1'*32 + w1
    int mm = (o & 31) * 32 + (s & 31);   // h2'*32 + w2
    S[((size_t)img << 20) + n * 1024 + mm] = __float2half(val);
  }
};
struct EpiPV {   // rows n, cols d -> O[(bp*1024+n)][h*64+d]
  __half* O;
  DEV void store(int img, int n, int d, float v) const {
    int bp = img >> 3, h = img & 7;
    O[((size_t)(bp * 1024 + n)) * 512 + h * 64 + d] = __float2half(v);
  }
};
struct EpiOut {  // rows t, cols j -> out f32 + bias
  float* out; const float* bias;
  DEV void store(int, int t, int j, float v) const {
    out[(size_t)t * 256 + j] = v + bias[j];
  }
};

// ---------------- fused depthwise convs as LDS-tiled transpose ----------------
// block = (img, h1). For each w1: read D rows n0=h1*32+w1, n1 (contiguous, coalesced),
// 4-tap conv in registers (per-thread channel weights), transpose (h2,w2)->(w2,h2)
// through padded LDS, write AC[s=w1*32+w2][c=h1*32+h2] coalesced.
__global__ __launch_bounds__(256) void conv_t_kernel(const __half* __restrict__ D,
    const float* __restrict__ wc1, const float* __restrict__ wc2,
    __half* __restrict__ AC) {
  const int img = blockIdx.x >> 5, h1 = blockIdx.x & 31;
  const __half* Di = D + ((size_t)img << 20) + (size_t)h1 * 32768;  // rows n = h1*32 + w1
  __half* ACi = AC + ((size_t)img << 20) + h1 * 32;
  const int tid = threadIdx.x;
  const int h2 = tid >> 3;          // channel-in-block (fixed per thread)
  const int w2 = (tid & 7) * 4;     // first w2 of this thread's 4 elems
  const int m = tid * 4;            // = h2*32 + w2
  const int c = h1 * 32 + h2;
  const float u0 = wc1[2 * c], u1 = wc1[2 * c + 1];   // conv along w2
  const float v0 = wc2[2 * c], v1 = wc2[2 * c + 1];   // conv along w1
  const int w2o = tid >> 3, h2o = (tid & 7) * 4;      // write-phase mapping
  __shared__ __half T[32][36];                        // [w2][h2], padded
  for (int w1 = 0; w1 < 32; ++w1) {
    const int w1n = (w1 < 31) ? w1 + 1 : 30;          // reflect bottom
    const __half* r0 = Di + w1 * 1024;
    const __half* r1 = Di + w1n * 1024;
    float a0[5], a1[5];
    ushort4 x0 = *reinterpret_cast<const ushort4*>(r0 + m);
    ushort4 x1 = *reinterpret_cast<const ushort4*>(r1 + m);
    a0[0] = h2f_bits(x0.x); a0[1] = h2f_bits(x0.y); a0[2] = h2f_bits(x0.z); a0[3] = h2f_bits(x0.w);
    a1[0] = h2f_bits(x1.x); a1[1] = h2f_bits(x1.y); a1[2] = h2f_bits(x1.z); a1[3] = h2f_bits(x1.w);
    if (w2 != 28) { a0[4] = __half2float(r0[m + 4]); a1[4] = __half2float(r1[m + 4]); }
    else          { a0[4] = 0.f;                      a1[4] = 0.f; }
#pragma unroll
    for (int j = 0; j < 4; ++j) {
      int jn = (w2 + j < 31) ? j + 1 : j - 1;         // reflect right (w2=31 -> 30)
      float val = v0 * (u0 * a0[j] + u1 * a0[jn]) + v1 * (u0 * a1[j] + u1 * a1[jn]);
      T[w2 + j][h2] = __float2half(val);
    }
    __syncthreads();
    ushort4 o = *reinterpret_cast<const ushort4*>(&T[w2o][h2o]);
    *reinterpret_cast<ushort4*>(ACi + (size_t)(w1 * 32 + w2o) * 1024 + h2o) = o;
    __syncthreads();
  }
}

// ---------------- row softmax: S[row][0..1024) f16 -> P f16 ----------------
__global__ __launch_bounds__(256) void softmax_kernel(const __half* __restrict__ S,
                                                      __half* __restrict__ P) {
  int row = blockIdx.x;
  int tid = threadIdx.x, lane = tid & 63, wid = tid >> 6;
  const __half* Sr = S + ((size_t)row << 10);
  ushort4 raw = reinterpret_cast<const ushort4*>(Sr)[tid];
  float v0 = h2f_bits(raw.x), v1 = h2f_bits(raw.y), v2 = h2f_bits(raw.z), v3 = h2f_bits(raw.w);
  float mx = fmaxf(fmaxf(v0, v1), fmaxf(v2, v3));
#pragma unroll
  for (int off = 32; off; off >>= 1) mx = fmaxf(mx, __shfl_xor(mx, off));
  __shared__ float rm[4], rsum[4];
  if (lane == 0) rm[wid] = mx;
  __syncthreads();
  mx = fmaxf(fmaxf(rm[0], rm[1]), fmaxf(rm[2], rm[3]));
  float e0 = __expf(v0 - mx), e1 = __expf(v1 - mx), e2 = __expf(v2 - mx), e3 = __expf(v3 - mx);
  float sm = e0 + e1 + e2 + e3;
#pragma unroll
  for (int off = 32; off; off >>= 1) sm += __shfl_xor(sm, off);
  if (lane == 0) rsum[wid] = sm;
  __syncthreads();
  sm = rsum[0] + rsum[1] + rsum[2] + rsum[3];
  float inv = 1.f / sm;
  ushort4 o4;
  o4.x = f2h_bits(e0 * inv); o4.y = f2h_bits(e1 * inv);
  o4.z = f2h_bits(e2 * inv); o4.w = f2h_bits(e3 * inv);
  reinterpret_cast<ushort4*>(P + ((size_t)row << 10))[tid] = o4;
}

extern "C" void kernel_launch(void* const* d_in, const int* in_sizes, int n_in,
                              void* d_out, int out_size, void* d_ws, size_t ws_size,
                              hipStream_t stream) {
  const float* x     = (const float*)d_in[0];
  const float* ln_g  = (const float*)d_in[1];
  const float* ln_b  = (const float*)d_in[2];
  const float* w_qkv = (const float*)d_in[3];
  const float* wc1   = (const float*)d_in[4];
  const float* wc2   = (const float*)d_in[5];
  const float* w1x1  = (const float*)d_in[6];
  const float* bn_g  = (const float*)d_in[7];
  const float* bn_b  = (const float*)d_in[8];
  const float* bn_m  = (const float*)d_in[9];
  const float* bn_v  = (const float*)d_in[10];
  const float* w_out = (const float*)d_in[11];
  const float* b_out = (const float*)d_in[12];
  float* out = (float*)d_out;

  const size_t MB = 1024 * 1024;
  char* ws = (char*)d_ws;
  // region0 (64MB): D (QK output), later overwritten by S (1x1 output)
  __half* Db = (__half*)ws;
  __half* Sh = (__half*)ws;
  // region1 (64MB): Aconv^T, later overwritten by P (softmax output)
  __half* ACb = (__half*)(ws + 64 * MB);
  __half* Pb  = ACb;
  // statics
  char* p = ws + 128 * MB;
  __half* XN    = (__half*)p; p += 2 * MB;            // 4096x256
  __half* WQKVT = (__half*)p; p += 1536 * 256 * 2;    // 1536x256
  __half* W1X1H = (__half*)p; p += 2 * MB;            // 1024x1024
  __half* WOTT  = (__half*)p; p += 256 * 512 * 2;     // 256x512
  __half* Qb    = (__half*)p; p += 4 * MB;            // 32x1024x64 (scaled)
  __half* Kb    = (__half*)p; p += 4 * MB;            // 32x1024x64
  __half* Vtb   = (__half*)p; p += 4 * MB;            // 32x64x1024
  __half* Ob    = (__half*)p; p += 4 * MB;            // 4096x512

  prep_kernel<<<2048, 256, 0, stream>>>(w_qkv, w1x1, w_out, WQKVT, W1X1H, WOTT);
  ln_kernel<<<4096, 256, 0, stream>>>(x, ln_g, ln_b, XN);

  { EpiQKV e{Qb, Kb, Vtb};
    gemm_bt<128, 128, 64, 2, 4, 4, EpiQKV><<<dim3(32, 12, 1), 256, 0, stream>>>(
        XN, 0, WQKVT, 0, 256, e); }

  { EpiQK e{Db};
    gemm_bt<128, 128, 64, 2, 4, 4, EpiQK><<<dim3(8, 8, 32), 256, 0, stream>>>(
        Qb, 65536, Kb, 65536, 64, e); }

  conv_t_kernel<<<1024, 256, 0, stream>>>(Db, wc1, wc2, ACb);

  { Epi1x1 e{Sh, bn_g, bn_b, bn_m, bn_v};
    gemm_bt<128, 128, 64, 2, 4, 4, Epi1x1><<<dim3(8, 8, 32), 256, 0, stream>>>(
        W1X1H, 0, ACb, 1 << 20, 1024, e); }

  softmax_kernel<<<32768, 256, 0, stream>>>(Sh, Pb);

  { EpiPV e{Ob};
    gemm_bt<128, 64, 64, 2, 4, 2, EpiPV><<<dim3(8, 1, 32), 256, 0, stream>>>(
        Pb, 1 << 20, Vtb, 65536, 1024, e); }

  { EpiOut e{out, b_out};
    gemm_bt<128, 128, 64, 2, 4, 4, EpiOut><<<dim3(32, 2, 1), 256, 0, stream>>>(
        Ob, 0, WOTT, 0, 512, e); }
}

// Round 4
// 223.759 us; speedup vs baseline: 2.3845x; 1.2453x over previous
//
#include <hip/hip_runtime.h>
#include <hip/hip_fp16.h>

// AttentionQV0: LN -> QKV -> QK^T -> dw-convs -> 1x1 conv+BN+SiLU+softmax(fused) -> PV -> out proj
// B=2,P=2,N=1024,DIM=256,HEADS=8,DH=64,HW=32,C=1024. 32 "images" of 1024x1024 scores.
// Workspace: region0 64MB (D -> P), region1 64MB (AC), statics ~21MB.

#define DEV __device__ __forceinline__

typedef __attribute__((ext_vector_type(8))) _Float16 f16x8;
typedef __attribute__((ext_vector_type(4))) float f32x4;

DEV float h2f_bits(unsigned short u) { __half h; *reinterpret_cast<unsigned short*>(&h) = u; return __half2float(h); }
DEV unsigned short f2h_bits(float f) { __half h = __float2half(f); return *reinterpret_cast<unsigned short*>(&h); }

// ---------------- prep: cast/transpose weights to f16 ----------------
__global__ __launch_bounds__(256) void prep_kernel(
    const float* __restrict__ wqkv, const float* __restrict__ w1x1,
    const float* __restrict__ wout,
    __half* __restrict__ WQKVT, __half* __restrict__ W1X1H, __half* __restrict__ WOTT) {
  int i0 = blockIdx.x * 256 + threadIdx.x;
  int stride = gridDim.x * 256;
  for (int i = i0; i < 1536 * 256; i += stride) {          // WQKVT[j][k] = wqkv[k][j]
    int j = i >> 8, k = i & 255;
    WQKVT[i] = __float2half(wqkv[k * 1536 + j]);
  }
  for (int i = i0; i < 1024 * 1024; i += stride)           // straight cast (row o, col c)
    W1X1H[i] = __float2half(w1x1[i]);
  for (int i = i0; i < 256 * 512; i += stride) {           // WOTT[j][k] = wout[k][j]
    int j = i >> 9, k = i & 511;
    WOTT[i] = __float2half(wout[k * 256 + j]);
  }
}

// ---------------- LayerNorm (row = token, 256 threads) ----------------
__global__ __launch_bounds__(256) void ln_kernel(const float* __restrict__ x,
    const float* __restrict__ g, const float* __restrict__ b, __half* __restrict__ XN) {
  int row = blockIdx.x;
  int tid = threadIdx.x, lane = tid & 63, wid = tid >> 6;
  float xv = x[(size_t)row * 256 + tid];
  float s = xv, q = xv * xv;
#pragma unroll
  for (int off = 32; off; off >>= 1) { s += __shfl_xor(s, off); q += __shfl_xor(q, off); }
  __shared__ float rs[4], rq[4];
  if (lane == 0) { rs[wid] = s; rq[wid] = q; }
  __syncthreads();
  s = rs[0] + rs[1] + rs[2] + rs[3];
  q = rq[0] + rq[1] + rq[2] + rq[3];
  float mu = s * (1.f / 256.f);
  float var = q * (1.f / 256.f) - mu * mu;
  float r = rsqrtf(var + 1e-5f);
  XN[(size_t)row * 256 + tid] = __float2half((xv - mu) * r * g[tid] + b[tid]);
}

// ---------------- generic BT GEMM: C[i][j] = sum_k A[i][k]*B[j][k] ----------------
// 128-wide tiles, BK=64, 256 threads (4 waves), mfma_f32_16x16x32_f16.
// Double-buffered LDS, T3-minimum pipeline: issue next tile's global_load_lds
// BEFORE computing current; ONE barrier per iteration (its vmcnt(0) drain lands
// after compute has hidden the load latency). Chunk swizzle c^(r&7) on the
// global SOURCE (LDS dest linear) + same XOR on ds_read: conflict-free reads.
// XCD-aware block swizzle for L2 reuse (grids are %8==0).
template <int BM, int BN, int BK, int WGN, int FM, int FN, class Epi>
__global__ __launch_bounds__(256) void gemm_bt(
    const __half* __restrict__ A, long long aStride,
    const __half* __restrict__ B, long long bStride,
    int K, Epi epi) {
  constexpr int CPR = BK / 8;                 // 16B chunks per row
  constexpr int NCA = (BM * BK) / (8 * 256);
  constexpr int NCB = (BN * BK) / (8 * 256);
  constexpr int KSUB = BK / 32;               // mfma k-steps per tile
  __shared__ __align__(16) __half smA[2][BM * BK];
  __shared__ __align__(16) __half smB[2][BN * BK];
  const int tid = threadIdx.x;
  const int lane = tid & 63, wid = tid >> 6;
  const int wr = wid / WGN, wc = wid % WGN;
  const int gx = gridDim.x, gxy = gridDim.x * gridDim.y;
  const int nwg = gxy * gridDim.z;
  const int b_lin = blockIdx.x + blockIdx.y * gx + blockIdx.z * gxy;
  const int logical = (b_lin & 7) * (nwg >> 3) + (b_lin >> 3);
  const int bx = logical % gx, by = (logical / gx) % gridDim.y, bz = logical / gxy;
  const int img = bz;
  const int row0 = bx * BM;
  const int col0 = by * BN;
  const __half* Ab = A + (size_t)((long long)img * aStride);
  const __half* Bb = B + (size_t)((long long)img * bStride);
  f32x4 acc[FM][FN] = {};
  const int lr = lane & 15;
  const int kq = lane >> 4;                   // 0..3 (16B chunk within k-sub)

  auto stage = [&](int buf, int kt) {
#pragma unroll
    for (int it = 0; it < NCA; ++it) {
      int e = it * 256 + tid;
      int r = e / CPR, c = e % CPR;
      int sc = c ^ (r & 7);                   // inverse swizzle on SOURCE
      __builtin_amdgcn_global_load_lds(
          (const __attribute__((address_space(1))) unsigned int*)(Ab + (size_t)(row0 + r) * K + kt + sc * 8),
          (__attribute__((address_space(3))) unsigned int*)(&smA[buf][r * BK + c * 8]),
          16, 0, 0);
    }
#pragma unroll
    for (int it = 0; it < NCB; ++it) {
      int e = it * 256 + tid;
      int r = e / CPR, c = e % CPR;
      int sc = c ^ (r & 7);
      __builtin_amdgcn_global_load_lds(
          (const __attribute__((address_space(1))) unsigned int*)(Bb + (size_t)(col0 + r) * K + kt + sc * 8),
          (__attribute__((address_space(3))) unsigned int*)(&smB[buf][r * BK + c * 8]),
          16, 0, 0);
    }
  };

  const int NT = K / BK;
  stage(0, 0);
  __syncthreads();
  int cur = 0;
  for (int t = 0; t < NT; ++t) {
    if (t + 1 < NT) stage(cur ^ 1, (t + 1) * BK);   // prefetch next tile first
#pragma unroll
    for (int kk = 0; kk < KSUB; ++kk) {
      f16x8 av[FM], bv[FN];
#pragma unroll
      for (int i = 0; i < FM; ++i) {
        int row = wr * FM * 16 + i * 16 + lr;
        int ch = (kk * 4 + kq) ^ (lr & 7);    // swizzled read
        av[i] = *reinterpret_cast<const f16x8*>(&smA[cur][row * BK + ch * 8]);
      }
#pragma unroll
      for (int j = 0; j < FN; ++j) {
        int row = wc * FN * 16 + j * 16 + lr;
        int ch = (kk * 4 + kq) ^ (lr & 7);
        bv[j] = *reinterpret_cast<const f16x8*>(&smB[cur][row * BK + ch * 8]);
      }
#pragma unroll
      for (int i = 0; i < FM; ++i)
#pragma unroll
        for (int j = 0; j < FN; ++j)
          acc[i][j] = __builtin_amdgcn_mfma_f32_16x16x32_f16(av[i], bv[j], acc[i][j], 0, 0, 0);
    }
    __syncthreads();                                 // drains prefetch + read-done
    cur ^= 1;
  }

  if constexpr (Epi::FUSED) {
    epi.finalize(img, row0, col0, wr, wc, lane, acc);
  } else {
    const int orow = row0 + wr * FM * 16 + (lane >> 4) * 4;
    const int ocol = col0 + wc * FN * 16 + lr;
#pragma unroll
    for (int i = 0; i < FM; ++i)
#pragma unroll
      for (int j = 0; j < FN; ++j)
#pragma unroll
        for (int q = 0; q < 4; ++q)
          epi.store(img, orow + i * 16 + q, ocol + j * 16, acc[i][j][q]);
  }
}

// ---------------- epilogues ----------------
struct EpiQKV {  // rows t in [0,4096), cols j in [0,1536)
  static constexpr bool FUSED = false;
  __half *Q, *K, *V;
  DEV void store(int, int t, int j, float v) const {
    int part = j >> 9, inner = j & 511;
    int h = inner >> 6, d = inner & 63;
    int bp = t >> 10, n = t & 1023;
    size_t img = (size_t)(bp * 8 + h);
    if (part == 0)       Q[(img * 1024 + n) * 64 + d] = __float2half(v * 0.125f); // fold DH^-0.5
    else if (part == 1)  K[(img * 1024 + n) * 64 + d] = __float2half(v);
    else                 V[(img * 64 + d) * 1024 + n] = __float2half(v);          // V transposed
  }
  DEV void finalize(int, int, int, int, int, int, f32x4 (&)[4][4]) const {}
};
struct EpiQK {   // D[img][n][m], natural layout
  static constexpr bool FUSED = false;
  __half* D;
  DEV void store(int img, int n, int m, float v) const {
    D[((size_t)img << 20) + n * 1024 + m] = __float2half(v);
  }
  DEV void finalize(int, int, int, int, int, int, f32x4 (&)[4][4]) const {}
};
// 1x1 conv epilogue: BN + SiLU + full softmax, write P directly.
// A softmax row n=(o>>5)*32+(s>>5) is the 32x32 (o&31, s&31) sub-block, which
// lives entirely in ONE wave's 2x2 fragment group -> in-register wave reduce.
struct Epi1x1F {
  static constexpr bool FUSED = true;
  __half* P;
  const float *g, *b, *m, *vv;
  DEV void store(int, int, int, float) const {}
  DEV void finalize(int img, int row0, int col0, int wr, int wc, int lane,
                    f32x4 (&acc)[4][4]) const {
    const int lr = lane & 15, kq = lane >> 4;
    float vals[4][4][4];
#pragma unroll
    for (int i = 0; i < 4; ++i) {
#pragma unroll
      for (int q = 0; q < 4; ++q) {
        int o = row0 + wr * 64 + i * 16 + kq * 4 + q;
        float sc = rsqrtf(vv[o] + 1e-5f) * g[o];
        float mo = m[o], bo = b[o];
#pragma unroll
        for (int j = 0; j < 4; ++j) {
          float t = (acc[i][j][q] - mo) * sc + bo;
          vals[i][j][q] = t / (1.f + __expf(-t));       // SiLU
        }
      }
    }
#pragma unroll
    for (int ih = 0; ih < 2; ++ih) {
#pragma unroll
      for (int sh = 0; sh < 2; ++sh) {
        float mx = -1e30f;
#pragma unroll
        for (int di = 0; di < 2; ++di)
#pragma unroll
          for (int dj = 0; dj < 2; ++dj)
#pragma unroll
            for (int q = 0; q < 4; ++q)
              mx = fmaxf(mx, vals[ih * 2 + di][sh * 2 + dj][q]);
#pragma unroll
        for (int off = 32; off; off >>= 1) mx = fmaxf(mx, __shfl_xor(mx, off));
        float sm = 0.f;
#pragma unroll
        for (int di = 0; di < 2; ++di)
#pragma unroll
          for (int dj = 0; dj < 2; ++dj)
#pragma unroll
            for (int q = 0; q < 4; ++q) {
              float e = __expf(vals[ih * 2 + di][sh * 2 + dj][q] - mx);
              vals[ih * 2 + di][sh * 2 + dj][q] = e;
              sm += e;
            }
#pragma unroll
        for (int off = 32; off; off >>= 1) sm += __shfl_xor(sm, off);
        float inv = 1.f / sm;
#pragma unroll
        for (int di = 0; di < 2; ++di) {
          int i = ih * 2 + di;
#pragma unroll
          for (int q = 0; q < 4; ++q) {
            int o = row0 + wr * 64 + i * 16 + kq * 4 + q;
#pragma unroll
            for (int dj = 0; dj < 2; ++dj) {
              int j = sh * 2 + dj;
              int s = col0 + wc * 64 + j * 16 + lr;
              int n  = (o >> 5) * 32 + (s >> 5);
              int mm = (o & 31) * 32 + (s & 31);
              P[((size_t)img << 20) + n * 1024 + mm] = __float2half(vals[i][j][q] * inv);
            }
          }
        }
      }
    }
  }
};
struct EpiPV {   // rows n, cols d -> O[(bp*1024+n)][h*64+d]
  static constexpr bool FUSED = false;
  __half* O;
  DEV void store(int img, int n, int d, float v) const {
    int bp = img >> 3, h = img & 7;
    O[((size_t)(bp * 1024 + n)) * 512 + h * 64 + d] = __float2half(v);
  }
  DEV void finalize(int, int, int, int, int, int, f32x4 (&)[4][4]) const {}
};
struct EpiOut {  // rows t, cols j -> out f32 + bias
  static constexpr bool FUSED = false;
  float* out; const float* bias;
  DEV void store(int, int t, int j, float v) const {
    out[(size_t)t * 256 + j] = v + bias[j];
  }
  DEV void finalize(int, int, int, int, int, int, f32x4 (&)[4][4]) const {}
};

// ---------------- fused depthwise convs as LDS-tiled transpose ----------------
__global__ __launch_bounds__(256) void conv_t_kernel(const __half* __restrict__ D,
    const float* __restrict__ wc1, const float* __restrict__ wc2,
    __half* __restrict__ AC) {
  const int img = blockIdx.x >> 5, h1 = blockIdx.x & 31;
  const __half* Di = D + ((size_t)img << 20) + (size_t)h1 * 32768;  // rows n = h1*32 + w1
  __half* ACi = AC + ((size_t)img << 20) + h1 * 32;
  const int tid = threadIdx.x;
  const int h2 = tid >> 3;          // channel-in-block (fixed per thread)
  const int w2 = (tid & 7) * 4;     // first w2 of this thread's 4 elems
  const int m = tid * 4;            // = h2*32 + w2
  const int c = h1 * 32 + h2;
  const float u0 = wc1[2 * c], u1 = wc1[2 * c + 1];   // conv along w2
  const float v0 = wc2[2 * c], v1 = wc2[2 * c + 1];   // conv along w1
  const int w2o = tid >> 3, h2o = (tid & 7) * 4;      // write-phase mapping
  __shared__ __half T[32][36];                        // [w2][h2], padded
  for (int w1 = 0; w1 < 32; ++w1) {
    const int w1n = (w1 < 31) ? w1 + 1 : 30;          // reflect bottom
    const __half* r0 = Di + w1 * 1024;
    const __half* r1 = Di + w1n * 1024;
    float a0[5], a1[5];
    ushort4 x0 = *reinterpret_cast<const ushort4*>(r0 + m);
    ushort4 x1 = *reinterpret_cast<const ushort4*>(r1 + m);
    a0[0] = h2f_bits(x0.x); a0[1] = h2f_bits(x0.y); a0[2] = h2f_bits(x0.z); a0[3] = h2f_bits(x0.w);
    a1[0] = h2f_bits(x1.x); a1[1] = h2f_bits(x1.y); a1[2] = h2f_bits(x1.z); a1[3] = h2f_bits(x1.w);
    if (w2 != 28) { a0[4] = __half2float(r0[m + 4]); a1[4] = __half2float(r1[m + 4]); }
    else          { a0[4] = 0.f;                      a1[4] = 0.f; }
#pragma unroll
    for (int j = 0; j < 4; ++j) {
      int jn = (w2 + j < 31) ? j + 1 : j - 1;         // reflect right (w2=31 -> 30)
      float val = v0 * (u0 * a0[j] + u1 * a0[jn]) + v1 * (u0 * a1[j] + u1 * a1[jn]);
      T[w2 + j][h2] = __float2half(val);
    }
    __syncthreads();
    ushort4 o = *reinterpret_cast<const ushort4*>(&T[w2o][h2o]);
    *reinterpret_cast<ushort4*>(ACi + (size_t)(w1 * 32 + w2o) * 1024 + h2o) = o;
    __syncthreads();
  }
}

extern "C" void kernel_launch(void* const* d_in, const int* in_sizes, int n_in,
                              void* d_out, int out_size, void* d_ws, size_t ws_size,
                              hipStream_t stream) {
  const float* x     = (const float*)d_in[0];
  const float* ln_g  = (const float*)d_in[1];
  const float* ln_b  = (const float*)d_in[2];
  const float* w_qkv = (const float*)d_in[3];
  const float* wc1   = (const float*)d_in[4];
  const float* wc2   = (const float*)d_in[5];
  const float* w1x1  = (const float*)d_in[6];
  const float* bn_g  = (const float*)d_in[7];
  const float* bn_b  = (const float*)d_in[8];
  const float* bn_m  = (const float*)d_in[9];
  const float* bn_v  = (const float*)d_in[10];
  const float* w_out = (const float*)d_in[11];
  const float* b_out = (const float*)d_in[12];
  float* out = (float*)d_out;

  const size_t MB = 1024 * 1024;
  char* ws = (char*)d_ws;
  // region0 (64MB): D (QK output), later overwritten by P (fused 1x1 output)
  __half* Db = (__half*)ws;
  __half* Pb = (__half*)ws;
  // region1 (64MB): Aconv^T
  __half* ACb = (__half*)(ws + 64 * MB);
  // statics
  char* p = ws + 128 * MB;
  __half* XN    = (__half*)p; p += 2 * MB;            // 4096x256
  __half* WQKVT = (__half*)p; p += 1536 * 256 * 2;    // 1536x256
  __half* W1X1H = (__half*)p; p += 2 * MB;            // 1024x1024
  __half* WOTT  = (__half*)p; p += 256 * 512 * 2;     // 256x512
  __half* Qb    = (__half*)p; p += 4 * MB;            // 32x1024x64 (scaled)
  __half* Kb    = (__half*)p; p += 4 * MB;            // 32x1024x64
  __half* Vtb   = (__half*)p; p += 4 * MB;            // 32x64x1024
  __half* Ob    = (__half*)p; p += 4 * MB;            // 4096x512

  prep_kernel<<<2048, 256, 0, stream>>>(w_qkv, w1x1, w_out, WQKVT, W1X1H, WOTT);
  ln_kernel<<<4096, 256, 0, stream>>>(x, ln_g, ln_b, XN);

  { EpiQKV e{Qb, Kb, Vtb};
    gemm_bt<128, 128, 64, 2, 4, 4, EpiQKV><<<dim3(32, 12, 1), 256, 0, stream>>>(
        XN, 0, WQKVT, 0, 256, e); }

  { EpiQK e{Db};
    gemm_bt<128, 128, 64, 2, 4, 4, EpiQK><<<dim3(8, 8, 32), 256, 0, stream>>>(
        Qb, 65536, Kb, 65536, 64, e); }

  conv_t_kernel<<<1024, 256, 0, stream>>>(Db, wc1, wc2, ACb);

  { Epi1x1F e{Pb, bn_g, bn_b, bn_m, bn_v};
    gemm_bt<128, 128, 64, 2, 4, 4, Epi1x1F><<<dim3(8, 8, 32), 256, 0, stream>>>(
        W1X1H, 0, ACb, 1 << 20, 1024, e); }

  { EpiPV e{Ob};
    gemm_bt<128, 64, 64, 2, 4, 2, EpiPV><<<dim3(8, 1, 32), 256, 0, stream>>>(
        Pb, 1 << 20, Vtb, 65536, 1024, e); }

  { EpiOut e{out, b_out};
    gemm_bt<128, 128, 64, 2, 4, 4, EpiOut><<<dim3(32, 2, 1), 256, 0, stream>>>(
        Ob, 0, WOTT, 0, 512, e); }
}